// Round 5
// baseline (350.939 us; speedup 1.0000x reference)
//
#include <hip/hip_runtime.h>

using u16    = unsigned short;
using short8 = __attribute__((ext_vector_type(8))) short;
using u16x8  = __attribute__((ext_vector_type(8))) u16;
using u16x4  = __attribute__((ext_vector_type(4))) u16;
using f32x4  = __attribute__((ext_vector_type(4))) float;

#define M_DIM 8192   // B*S = 16*512
#define N_DIM 1024   // D_OUT
#define K_DIM 4096   // D_IN

typedef __attribute__((address_space(1))) void gvoid;
typedef __attribute__((address_space(3))) void svoid;
#define GLOAD_LDS16(g, s) \
  __builtin_amdgcn_global_load_lds((gvoid*)(void*)(g), (svoid*)(s), 16, 0, 0)

__device__ __forceinline__ u16 f2bf(float f) {
  unsigned u = __builtin_bit_cast(unsigned, f);
  u = (u + 0x7FFFu + ((u >> 16) & 1u)) >> 16;   // RNE
  return (u16)u;
}

// ---- kernel 1: per-row alpha = mean|W|, Wsgn = sign(W) as bf16 (+1/-1/0 exact)
__global__ __launch_bounds__(256) void wprep_kernel(const float* __restrict__ W,
                                                    u16* __restrict__ Wsgn,
                                                    float* __restrict__ alpha) {
  const int row = blockIdx.x;
  const int t   = threadIdx.x;
  const float4* wr = (const float4*)(W + (size_t)row * K_DIM);
  float4 v[4];
  float s = 0.f;
#pragma unroll
  for (int j = 0; j < 4; ++j) {
    v[j] = wr[t + 256 * j];
    s += fabsf(v[j].x) + fabsf(v[j].y) + fabsf(v[j].z) + fabsf(v[j].w);
  }
#pragma unroll
  for (int off = 32; off > 0; off >>= 1) s += __shfl_down(s, off, 64);
  __shared__ float red[4];
  if ((t & 63) == 0) red[t >> 6] = s;
  __syncthreads();
  if (t == 0) alpha[row] = (red[0] + red[1] + red[2] + red[3]) * (1.0f / K_DIM);
  u16x4* dst = (u16x4*)(Wsgn + (size_t)row * K_DIM);
#pragma unroll
  for (int j = 0; j < 4; ++j) {
    u16x4 sg;
    sg[0] = v[j].x > 0.f ? 0x3F80 : (v[j].x < 0.f ? 0xBF80 : 0);
    sg[1] = v[j].y > 0.f ? 0x3F80 : (v[j].y < 0.f ? 0xBF80 : 0);
    sg[2] = v[j].z > 0.f ? 0x3F80 : (v[j].z < 0.f ? 0xBF80 : 0);
    sg[3] = v[j].w > 0.f ? 0x3F80 : (v[j].w < 0.f ? 0xBF80 : 0);
    dst[t + 256 * j] = sg;
  }
}

// ---- kernel 2: hidden fp32 -> bf16 (8 elems/thread)
__global__ __launch_bounds__(256) void cast_kernel(const float* __restrict__ in,
                                                   u16* __restrict__ out) {
  const size_t i = ((size_t)blockIdx.x * 256 + threadIdx.x) * 8;
  float4 a = ((const float4*)(in + i))[0];
  float4 b = ((const float4*)(in + i))[1];
  u16x8 p;
  p[0] = f2bf(a.x); p[1] = f2bf(a.y); p[2] = f2bf(a.z); p[3] = f2bf(a.w);
  p[4] = f2bf(b.x); p[5] = f2bf(b.y); p[6] = f2bf(b.z); p[7] = f2bf(b.w);
  *(u16x8*)(out + i) = p;
}

// ---- kernel 3: GEMM C[m,n] = sum_k A[m,k]*Wsgn[n,k], epilogue *alpha + b + resid
// Round 9: T4 counted-vmcnt pipeline. R4 proved drain-at-barrier == no pipeline
// (catalog m218: "8-phase-with-drain0 ~= 1-phase"); the validated lever is loads
// IN FLIGHT ACROSS barriers. Structure: BK=32, FOUR LDS buffers (4x16KB=64KB,
// still 2 blocks/CU), prefetch distance 2, raw s_barrier (no __syncthreads in
// the loop), per-iter wait = s_waitcnt vmcnt(8): each wave's own 4 DMA ops for
// tile j retire (in-order), tiles j+1/j+2 (8 ops) stay outstanding.
//   iter j: STAGE(j+2 -> buf[(j+2)&3]); vmcnt(8); s_barrier; COMPUTE(buf[j&3])
// Race audit (D=4): stager of j+2 can only be concurrent with readers of
// j-1 (diff 3), j (diff 2), j+1 (diff 1) -- all distinct buffers; j-2 readers
// are fenced by barrier j-1.
// LDS layout per buffer: [128 rows][4 slots x 16 B]; slot s holds k-granule
// s ^ ((row ^ row>>2) & 3)  (2-way max on fragment ds_read_b128 = free);
// inverse permutation folded into per-lane DMA SOURCE addr, dest stays linear.
template <bool PRE>
__global__ __launch_bounds__(256) void gemm_kernel(const void* __restrict__ Aopaque,
                                                   const u16* __restrict__ Bsgn,
                                                   const float* __restrict__ alpha,
                                                   const float* __restrict__ bias,
                                                   const float* __restrict__ resid,
                                                   float* __restrict__ out) {
  __shared__ u16 lA[4][128 * 32];   // 4 x 8 KB
  __shared__ u16 lB[4][128 * 32];   // 4 x 8 KB
  const int tid  = threadIdx.x;
  const int wave = tid >> 6;
  const int lane = tid & 63;
  const int quad = lane >> 4;
  const int l16  = lane & 15;
  const int wm   = (wave >> 1) * 64;
  const int wn   = (wave & 1) * 64;

  // XCD swizzle: 512 blocks; xcd = b&7 owns M-bands, all 8 N-tiles per band.
  const int b    = blockIdx.x;
  const int xcd  = b & 7;
  const int l    = b >> 3;                        // 0..63
  const size_t m0 = (size_t)(xcd * 8 + (l >> 3)) * 128;
  const size_t n0 = (size_t)(l & 7) * 128;

  f32x4 acc[4][4] = {};

  // DMA staging: per matrix-tile 8 chunks x 1 KB (16 rows x 4 slots x 16 B),
  // 2 chunks/wave. lane -> (r16 = lane>>2 row-in-chunk, sl = lane&3 dest slot).
  // source granule g = sl ^ ((row ^ row>>2)&3); row&3 = r16&3, (row>>2)&3 = quad
  // of lane -> g is lane-constant.
  const int r16 = lane >> 2;
  const int sl  = lane & 3;
  const int g   = sl ^ ((r16 ^ (r16 >> 2)) & 3);
  const u16* bsrc[2];
  const u16* asrc16[2];
  int        coff[2];
#pragma unroll
  for (int j = 0; j < 2; ++j) {
    const int c   = wave * 2 + j;                 // chunk 0..7
    const int row = c * 16 + r16;                 // local row 0..127
    bsrc[j] = Bsgn + (n0 + (size_t)row) * K_DIM + g * 8;
    if constexpr (PRE)
      asrc16[j] = (const u16*)Aopaque + (m0 + (size_t)row) * K_DIM + g * 8;
    coff[j] = c * 512 + lane * 8;                 // u16 offset inside 8 KB buf
  }

  // fragment addressing: slot = quad ^ ((row ^ row>>2)&3); row = wm+mt*16+l16
  // -> xor term = (l16 ^ (l16>>2))&3, lane-constant across mt/nt.
  const int fx    = (l16 ^ (l16 >> 2)) & 3;
  const int slot8 = (quad ^ fx) * 8;              // u16 offset of lane's granule

#define STAGE(K0, BUF)                                                         \
  do {                                                                         \
    u16* __a = &lA[BUF][0];                                                    \
    u16* __b = &lB[BUF][0];                                                    \
    GLOAD_LDS16(bsrc[0] + (K0), __b + coff[0]);                                \
    GLOAD_LDS16(bsrc[1] + (K0), __b + coff[1]);                                \
    if constexpr (PRE) {                                                       \
      GLOAD_LDS16(asrc16[0] + (K0), __a + coff[0]);                            \
      GLOAD_LDS16(asrc16[1] + (K0), __a + coff[1]);                            \
    } else {                                                                   \
      const float* Af = (const float*)Aopaque;                                 \
      const int row = tid >> 1;                                                \
      const int h   = tid & 1;                                                 \
      const int xv  = (row ^ (row >> 2)) & 3;                                  \
      _Pragma("unroll")                                                        \
      for (int gg = 0; gg < 2; ++gg) {                                         \
        const int kg = h * 2 + gg;                                             \
        const float4* src = (const float4*)(Af + (m0 + row) * (size_t)K_DIM +  \
                                            (K0) + kg * 8);                    \
        float4 f0 = src[0], f1 = src[1];                                       \
        u16x8 p;                                                               \
        p[0] = f2bf(f0.x); p[1] = f2bf(f0.y); p[2] = f2bf(f0.z); p[3] = f2bf(f0.w); \
        p[4] = f2bf(f1.x); p[5] = f2bf(f1.y); p[6] = f2bf(f1.z); p[7] = f2bf(f1.w); \
        *(u16x8*)(__a + row * 32 + ((kg ^ xv) * 8)) = p;                       \
      }                                                                        \
    }                                                                          \
  } while (0)

#define WAIT_STEADY()                                                          \
  do {                                                                         \
    if constexpr (PRE) asm volatile("s_waitcnt vmcnt(8)" ::: "memory");        \
    else asm volatile("s_waitcnt vmcnt(0) lgkmcnt(0)" ::: "memory");           \
  } while (0)

#define WAIT_N(N)                                                              \
  do {                                                                         \
    if constexpr (PRE) asm volatile("s_waitcnt vmcnt(" #N ")" ::: "memory");   \
    else asm volatile("s_waitcnt vmcnt(0) lgkmcnt(0)" ::: "memory");           \
  } while (0)

#define BARRIER()                                                              \
  do {                                                                         \
    __builtin_amdgcn_s_barrier();                                              \
    asm volatile("" ::: "memory");                                             \
  } while (0)

#define COMPUTE(BUF)                                                           \
  do {                                                                         \
    const u16* __a = &lA[BUF][0];                                              \
    const u16* __b = &lB[BUF][0];                                              \
    short8 af[4], bf[4];                                                       \
    _Pragma("unroll")                                                          \
    for (int mt = 0; mt < 4; ++mt)                                             \
      af[mt] = *(const short8*)(__a + (wm + mt * 16 + l16) * 32 + slot8);      \
    _Pragma("unroll")                                                          \
    for (int nt = 0; nt < 4; ++nt)                                             \
      bf[nt] = *(const short8*)(__b + (wn + nt * 16 + l16) * 32 + slot8);      \
    _Pragma("unroll")                                                          \
    for (int mt = 0; mt < 4; ++mt)                                             \
      _Pragma("unroll")                                                        \
      for (int nt = 0; nt < 4; ++nt)                                           \
        acc[mt][nt] = __builtin_amdgcn_mfma_f32_16x16x32_bf16(af[mt], bf[nt],  \
                                                              acc[mt][nt], 0, 0, 0); \
  } while (0)

  // prologue: tiles 0,1 into bufs 0,1 (12 own DMA outstanding after iter-0 STAGE)
  STAGE(0, 0);
  STAGE(32, 1);

#pragma unroll 1
  for (int j = 0; j < 126; ++j) {
    STAGE((j + 2) * 32, (j + 2) & 3);
    WAIT_STEADY();          // retire tile j's 4 ops; j+1, j+2 stay in flight
    BARRIER();
    COMPUTE(j & 3);
  }
  // tail: tiles 126, 127 (no more stages; drain progressively)
  WAIT_N(4);
  BARRIER();
  COMPUTE(2);               // 126 & 3
  WAIT_N(0);
  BARRIER();
  COMPUTE(3);               // 127 & 3

  // epilogue: x = acc*alpha[n] + b[n] + resid ; C/D map: col=l16, row=quad*4+r
#pragma unroll
  for (int nt = 0; nt < 4; ++nt) {
    const size_t n  = n0 + wn + nt * 16 + l16;
    const float  al = alpha[n];
    const float  bi = bias[n];
#pragma unroll
    for (int mt = 0; mt < 4; ++mt) {
      const size_t mbase = m0 + wm + mt * 16 + quad * 4;
#pragma unroll
      for (int r = 0; r < 4; ++r) {
        const size_t mm = mbase + r;
        out[mm * N_DIM + n] = acc[mt][nt][r] * al + bi + resid[mm * N_DIM + n];
      }
    }
  }
#undef STAGE
#undef WAIT_STEADY
#undef WAIT_N
#undef BARRIER
#undef COMPUTE
}

// ---- kernel 4: LayerNorm over last dim (1024), in-place on d_out
__global__ __launch_bounds__(256) void ln_kernel(float* __restrict__ x,
                                                 const float* __restrict__ gamma,
                                                 const float* __restrict__ beta) {
  const size_t row = blockIdx.x;
  float4* xr = (float4*)(x + row * N_DIM);
  const int t = threadIdx.x;
  float4 v = xr[t];
  float s  = v.x + v.y + v.z + v.w;
  float sq = v.x * v.x + v.y * v.y + v.z * v.z + v.w * v.w;
#pragma unroll
  for (int off = 32; off > 0; off >>= 1) {
    s  += __shfl_down(s, off, 64);
    sq += __shfl_down(sq, off, 64);
  }
  __shared__ float rs[4], rq[4];
  if ((t & 63) == 0) { rs[t >> 6] = s; rq[t >> 6] = sq; }
  __syncthreads();
  s  = rs[0] + rs[1] + rs[2] + rs[3];
  sq = rq[0] + rq[1] + rq[2] + rq[3];
  const float mu  = s * (1.0f / N_DIM);
  float var = sq * (1.0f / N_DIM) - mu * mu;
  var = fmaxf(var, 0.0f);
  const float inv = rsqrtf(var + 1e-12f);
  const float4 g = ((const float4*)gamma)[t];
  const float4 b = ((const float4*)beta)[t];
  v.x = g.x * ((v.x - mu) * inv) + b.x;
  v.y = g.y * ((v.y - mu) * inv) + b.y;
  v.z = g.z * ((v.z - mu) * inv) + b.z;
  v.w = g.w * ((v.w - mu) * inv) + b.w;
  xr[t] = v;
}

extern "C" void kernel_launch(void* const* d_in, const int* in_sizes, int n_in,
                              void* d_out, int out_size, void* d_ws, size_t ws_size,
                              hipStream_t stream) {
  const float* hidden = (const float*)d_in[0];  // [16,512,4096]
  const float* resid  = (const float*)d_in[1];  // [16,512,1024]
  const float* W      = (const float*)d_in[2];  // [1024,4096]
  const float* bias   = (const float*)d_in[3];  // [1024]
  const float* gamma  = (const float*)d_in[4];  // [1024]
  const float* beta   = (const float*)d_in[5];  // [1024]
  float* out = (float*)d_out;                   // [16,512,1024] fp32

  char* ws = (char*)d_ws;
  u16*   Wsgn  = (u16*)ws;                                   // 8 MiB
  float* alpha = (float*)(ws + 8ull * 1024 * 1024);          // 4 KiB
  u16*   Abf   = (u16*)(ws + 8ull * 1024 * 1024 + 4096);     // 64 MiB (path A)
  const size_t need_full = 8ull * 1024 * 1024 + 4096 + 64ull * 1024 * 1024;

  wprep_kernel<<<N_DIM, 256, 0, stream>>>(W, Wsgn, alpha);

  const int nblocks = (N_DIM / 128) * (M_DIM / 128);  // 512, 1D swizzled grid
  if (ws_size >= need_full) {
    cast_kernel<<<(M_DIM * (size_t)K_DIM) / (256 * 8), 256, 0, stream>>>(hidden, Abf);
    gemm_kernel<true><<<nblocks, 256, 0, stream>>>((const void*)Abf, Wsgn, alpha,
                                                   bias, resid, out);
  } else {
    gemm_kernel<false><<<nblocks, 256, 0, stream>>>((const void*)hidden, Wsgn, alpha,
                                                    bias, resid, out);
  }
  ln_kernel<<<M_DIM, 256, 0, stream>>>(out, gamma, beta);
}